// Round 1
// baseline (294.660 us; speedup 1.0000x reference)
//
#include <hip/hip_runtime.h>
#include <math.h>

#define B_    32
#define T_    512
#define M_    2048
#define L_    1024
#define NMEL_ 80
#define DSPK_ 256

// ws layout (floats): [0]=mel_abs_sum, [1]=postnet_abs_sum,
//                     [2..33]=S1[b] (attn masked sum), [34..65]=S2[b] (attn*diag sum)
#define WS_N 66

__global__ void init_ws_kernel(float* __restrict__ ws) {
    int i = threadIdx.x;
    if (i < WS_N) ws[i] = 0.0f;
}

// reduce two values across a 256-thread block; result valid on thread 0 only
__device__ __forceinline__ void blk_reduce2(float& a, float& b) {
    #pragma unroll
    for (int off = 32; off > 0; off >>= 1) {
        a += __shfl_down(a, off);
        b += __shfl_down(b, off);
    }
    __shared__ float la[4], lb[4];
    int lane = threadIdx.x & 63, w = threadIdx.x >> 6;
    if (lane == 0) { la[w] = a; lb[w] = b; }
    __syncthreads();
    if (threadIdx.x == 0) {
        a = la[0] + la[1] + la[2] + la[3];
        b = lb[0] + lb[1] + lb[2] + lb[3];
    }
}

// ---- mel MAE sums: grid-stride over float4 groups, skip padded rows ----
__global__ void mel_kernel(const float* __restrict__ mel_t,
                           const float* __restrict__ mel_p,
                           const float* __restrict__ post_p,
                           const int*   __restrict__ mel_lens,
                           float* __restrict__ ws) {
    const int N4 = B_ * M_ * NMEL_ / 4;   // 1,310,720 float4 groups (NMEL%4==0)
    float s0 = 0.0f, s1 = 0.0f;
    for (int i = blockIdx.x * blockDim.x + threadIdx.x; i < N4;
         i += gridDim.x * blockDim.x) {
        int row = i / (NMEL_ / 4);        // b*M + m   (20 groups per row)
        int b = row >> 11;                // / 2048
        int m = row & (M_ - 1);
        if (m < mel_lens[b]) {
            float4 t = ((const float4*)mel_t)[i];
            float4 p = ((const float4*)mel_p)[i];
            float4 q = ((const float4*)post_p)[i];
            s0 += fabsf(p.x - t.x) + fabsf(p.y - t.y) + fabsf(p.z - t.z) + fabsf(p.w - t.w);
            s1 += fabsf(q.x - t.x) + fabsf(q.y - t.y) + fabsf(q.z - t.z) + fabsf(q.w - t.w);
        }
    }
    blk_reduce2(s0, s1);
    if (threadIdx.x == 0) {
        atomicAdd(&ws[0], s0);
        atomicAdd(&ws[1], s1);
    }
}

// ---- attention S1/S2 per batch: one block handles 8 consecutive t-rows ----
#define ROWS_PER_BLK 8
__global__ void attn_kernel(const float* __restrict__ attn,   // [B,T,L]
                            const int* __restrict__ x_lengths,
                            const int* __restrict__ lip_length,
                            float* __restrict__ S1,
                            float* __restrict__ S2) {
    int blk   = blockIdx.x;                  // b*(T/ROWS) + chunk
    int b     = blk / (T_ / ROWS_PER_BLK);
    int chunk = blk % (T_ / ROWS_PER_BLK);
    int xl = x_lengths[b];
    int ll = lip_length[b];
    float ks = (float)ll / (float)xl;
    float da = (float)ll / 8.0f;             // DIAR = 8.0
    int l0 = threadIdx.x * 4;
    float s1 = 0.0f, s2 = 0.0f;
    const float* base = attn + ((size_t)b * T_ + (size_t)chunk * ROWS_PER_BLK) * L_;
    #pragma unroll
    for (int r = 0; r < ROWS_PER_BLK; ++r) {
        int t = chunk * ROWS_PER_BLK + r;
        if (t >= xl) continue;               // block-uniform; no barrier inside
        float tf = (float)t;
        // match numpy f32: non-fused mul then add/sub, then floor
        float y1f = floorf(__fadd_rn(__fmul_rn(ks, tf), da));
        float y2f = floorf(fmaxf(__fsub_rn(__fmul_rn(ks, tf), da), 0.0f));
        int y1i = (int)y1f, y2i = (int)y2f;
        float4 v = ((const float4*)(base + (size_t)r * L_))[threadIdx.x];
        float vv[4] = {v.x, v.y, v.z, v.w};
        #pragma unroll
        for (int j = 0; j < 4; ++j) {
            int l = l0 + j;
            if (l < ll) {
                s1 += vv[j];
                if (l >= y2i && l < y1i) s2 += vv[j];
            }
        }
    }
    blk_reduce2(s1, s2);
    if (threadIdx.x == 0) {
        atomicAdd(&S1[b], s1);
        atomicAdd(&S2[b], s2);
    }
}

// ---- finalize: duration MSE, speaker cosine, focus/diag, assemble outputs ----
__global__ void final_kernel(const int*   __restrict__ mel_lens,
                             const int*   __restrict__ dur_t,
                             const float* __restrict__ ldp,
                             const int*   __restrict__ x_lengths,
                             const float* __restrict__ spk_p,
                             const float* __restrict__ spk_e,
                             const float* __restrict__ ws,
                             float* __restrict__ out) {
    // duration MSE numerator (mask t < x_len)
    float sd = 0.0f;
    for (int i = threadIdx.x; i < B_ * T_; i += 256) {
        int b = i / T_, t = i % T_;
        if (t < x_lengths[b]) {
            float d = ldp[i] - logf((float)dur_t[i] + 1.0f);
            sd += d * d;
        }
    }
    float dummy = 0.0f;
    blk_reduce2(sd, dummy);
    __shared__ float sd_total;
    if (threadIdx.x == 0) sd_total = sd;

    // speaker cosine partials: 8 threads per b
    __shared__ float pn[256], p1[256], p2[256];
    {
        int b = threadIdx.x >> 3, j0 = threadIdx.x & 7;
        float num = 0.0f, n1 = 0.0f, n2 = 0.0f;
        for (int k = 0; k < DSPK_; k += 8) {
            float a = spk_p[b * DSPK_ + k + j0];
            float c = spk_e[b * DSPK_ + k + j0];
            num += a * c; n1 += a * a; n2 += c * c;
        }
        pn[threadIdx.x] = num; p1[threadIdx.x] = n1; p2[threadIdx.x] = n2;
    }
    __syncthreads();
    __shared__ float spk_l[B_];
    if (threadIdx.x < B_) {
        int base = threadIdx.x * 8;
        float N = 0.0f, A = 0.0f, C = 0.0f;
        for (int k = 0; k < 8; ++k) { N += pn[base + k]; A += p1[base + k]; C += p2[base + k]; }
        const float eps = 1e-6f;
        float cosv = N / (fmaxf(sqrtf(A), eps) * fmaxf(sqrtf(C), eps));
        spk_l[threadIdx.x] = 1.0f - cosv;
    }
    __syncthreads();

    if (threadIdx.x == 0) {
        float spk = 0.0f;
        for (int i = 0; i < B_; ++i) spk += spk_l[i];
        spk /= (float)B_;

        float sm = 0.0f;                       // sum of valid src positions
        for (int b = 0; b < B_; ++b) sm += (float)min(x_lengths[b], T_);
        float dur = sd_total / sm;

        float cnt = 0.0f;                      // valid mel frames * NMEL
        for (int b = 0; b < B_; ++b) cnt += (float)min(mel_lens[b], M_);
        cnt *= (float)NMEL_;
        float mel  = ws[0] / cnt;
        float post = ws[1] / cnt;

        float fm = 0.0f;                       // mean focus
        for (int b = 0; b < B_; ++b) fm += ws[34 + b] / ws[2 + b];
        fm /= (float)B_;
        float dia = 0.1f * (-logf(fm));

        out[0] = mel + post + dur + spk + dia;
        out[1] = mel;
        out[2] = post;
        out[3] = spk;
        out[4] = dur;
        out[5] = dia;
    }
}

extern "C" void kernel_launch(void* const* d_in, const int* in_sizes, int n_in,
                              void* d_out, int out_size, void* d_ws, size_t ws_size,
                              hipStream_t stream) {
    (void)in_sizes; (void)n_in; (void)out_size; (void)ws_size;
    const float* mel_t   = (const float*)d_in[2];
    const int*   mel_len = (const int*)  d_in[5];
    const int*   dur_t   = (const int*)  d_in[6];
    const float* mel_p   = (const float*)d_in[8];
    const float* post_p  = (const float*)d_in[9];
    const float* ldp     = (const float*)d_in[10];
    const float* spk_p   = (const float*)d_in[14];
    const float* spk_e   = (const float*)d_in[15];
    const float* attn    = (const float*)d_in[16];
    const int*   xl      = (const int*)  d_in[17];
    const int*   ll      = (const int*)  d_in[18];
    float* ws  = (float*)d_ws;
    float* out = (float*)d_out;

    hipLaunchKernelGGL(init_ws_kernel, dim3(1), dim3(128), 0, stream, ws);
    hipLaunchKernelGGL(mel_kernel, dim3(2048), dim3(256), 0, stream,
                       mel_t, mel_p, post_p, mel_len, ws);
    hipLaunchKernelGGL(attn_kernel, dim3(B_ * (T_ / ROWS_PER_BLK)), dim3(256), 0, stream,
                       attn, xl, ll, ws + 2, ws + 34);
    hipLaunchKernelGGL(final_kernel, dim3(1), dim3(256), 0, stream,
                       mel_len, dur_t, ldp, xl, spk_p, spk_e, ws, out);
}

// Round 2
// 181.275 us; speedup vs baseline: 1.6255x; 1.6255x over previous
//
#include <hip/hip_runtime.h>
#include <math.h>

#define B_    32
#define T_    512
#define M_    2048
#define L_    1024
#define NMEL_ 80
#define DSPK_ 256

// block-role partition of the fused kernel
#define NB_MEL  512            // 32 b x 16 chunks of 128 rows
#define NB_ATTN 1024           // 32 b x 32 chunks of 16 rows
#define NB_DUR  8              // 8 x 2048 elements
#define NB_SPK  32             // one per b
#define NB_TOT  (NB_MEL + NB_ATTN + NB_DUR + NB_SPK)

// ws layout (floats) — every slot written unconditionally by its owner block
#define WS_ATTN (NB_MEL * 2)
#define WS_DUR  (WS_ATTN + NB_ATTN * 2)
#define WS_SPK  (WS_DUR + NB_DUR)

__device__ __forceinline__ void red2(float& a, float& b) {
    __shared__ float la[4], lb[4];
    #pragma unroll
    for (int off = 32; off > 0; off >>= 1) {
        a += __shfl_down(a, off);
        b += __shfl_down(b, off);
    }
    int lane = threadIdx.x & 63, w = threadIdx.x >> 6;
    if (lane == 0) { la[w] = a; lb[w] = b; }
    __syncthreads();
    if (threadIdx.x == 0) {
        a = la[0] + la[1] + la[2] + la[3];
        b = lb[0] + lb[1] + lb[2] + lb[3];
    }
}

__device__ __forceinline__ void red3(float& a, float& b, float& c) {
    __shared__ float la[4], lb[4], lc[4];
    #pragma unroll
    for (int off = 32; off > 0; off >>= 1) {
        a += __shfl_down(a, off);
        b += __shfl_down(b, off);
        c += __shfl_down(c, off);
    }
    int lane = threadIdx.x & 63, w = threadIdx.x >> 6;
    if (lane == 0) { la[w] = a; lb[w] = b; lc[w] = c; }
    __syncthreads();
    if (threadIdx.x == 0) {
        a = la[0] + la[1] + la[2] + la[3];
        b = lb[0] + lb[1] + lb[2] + lb[3];
        c = lc[0] + lc[1] + lc[2] + lc[3];
    }
}

__device__ __forceinline__ float mae4(float4 p, float4 t) {
    return fabsf(p.x - t.x) + fabsf(p.y - t.y) + fabsf(p.z - t.z) + fabsf(p.w - t.w);
}

__device__ __forceinline__ void attn_row(float4 v, int t, float ks, float da,
                                         int l0, float m0, float m1, float m2, float m3,
                                         float& s1, float& s2) {
    float tf = (float)t;
    // match numpy f32: non-fused mul then add/sub, then floor (verified absmax 0)
    float y1f = floorf(__fadd_rn(__fmul_rn(ks, tf), da));
    float y2f = floorf(fmaxf(__fsub_rn(__fmul_rn(ks, tf), da), 0.0f));
    int y1i = (int)y1f, y2i = (int)y2f;
    float w0 = v.x * m0, w1 = v.y * m1, w2 = v.z * m2, w3 = v.w * m3;
    s1 += w0 + w1 + w2 + w3;
    s2 += ((l0 + 0 >= y2i) && (l0 + 0 < y1i)) ? w0 : 0.0f;
    s2 += ((l0 + 1 >= y2i) && (l0 + 1 < y1i)) ? w1 : 0.0f;
    s2 += ((l0 + 2 >= y2i) && (l0 + 2 < y1i)) ? w2 : 0.0f;
    s2 += ((l0 + 3 >= y2i) && (l0 + 3 < y1i)) ? w3 : 0.0f;
}

__global__ __launch_bounds__(256) void fused_kernel(
    const float* __restrict__ mel_t, const float* __restrict__ mel_p,
    const float* __restrict__ post_p, const int* __restrict__ mel_lens,
    const float* __restrict__ attn, const int* __restrict__ xl_,
    const int* __restrict__ ll_, const int* __restrict__ dur_t,
    const float* __restrict__ ldp, const float* __restrict__ spk_p,
    const float* __restrict__ spk_e, float* __restrict__ ws) {
    int blk = blockIdx.x, tid = threadIdx.x;

    if (blk < NB_MEL) {
        // ---- mel MAE partials: uniform trip count, unconditional unroll-2 loads ----
        int b = blk >> 4, chunk = blk & 15;
        int r0 = chunk << 7;                       // 128 rows per chunk
        int ml = mel_lens[b]; if (ml > M_) ml = M_;
        int rv = ml - r0; if (rv < 0) rv = 0; if (rv > 128) rv = 128;
        int n4 = rv * (NMEL_ / 4);                 // up to 2560 float4 groups
        const float4* t4 = (const float4*)mel_t + (size_t)(b * M_ + r0) * (NMEL_ / 4);
        const float4* p4 = (const float4*)mel_p + (size_t)(b * M_ + r0) * (NMEL_ / 4);
        const float4* q4 = (const float4*)post_p + (size_t)(b * M_ + r0) * (NMEL_ / 4);
        float s0 = 0.0f, s1 = 0.0f;
        int i = tid;
        for (; i + 256 < n4; i += 512) {
            float4 ta = t4[i],       pa = p4[i],       qa = q4[i];
            float4 tb = t4[i + 256], pb = p4[i + 256], qb = q4[i + 256];
            s0 += mae4(pa, ta) + mae4(pb, tb);
            s1 += mae4(qa, ta) + mae4(qb, tb);
        }
        if (i < n4) {
            float4 ta = t4[i], pa = p4[i], qa = q4[i];
            s0 += mae4(pa, ta);
            s1 += mae4(qa, ta);
        }
        red2(s0, s1);
        if (tid == 0) { ws[blk * 2] = s0; ws[blk * 2 + 1] = s1; }

    } else if (blk < NB_MEL + NB_ATTN) {
        // ---- attention S1/S2 partials: one row per iteration, uniform bound ----
        int a = blk - NB_MEL;
        int b = a >> 5, chunk = a & 31;
        int t0 = chunk << 4;                       // 16 rows per chunk
        int xl = xl_[b], ll = ll_[b];
        float ks = (float)ll / (float)xl;
        float da = (float)ll * 0.125f;             // DIAR = 8.0
        int tv = ((xl < t0 + 16) ? xl : (t0 + 16)) - t0; if (tv < 0) tv = 0;
        const float4* a4 = (const float4*)attn + ((size_t)b * T_ + t0) * (L_ / 4);
        int l0 = tid * 4;
        float m0 = (l0 + 0 < ll) ? 1.0f : 0.0f;
        float m1 = (l0 + 1 < ll) ? 1.0f : 0.0f;
        float m2 = (l0 + 2 < ll) ? 1.0f : 0.0f;
        float m3 = (l0 + 3 < ll) ? 1.0f : 0.0f;
        float s1 = 0.0f, s2 = 0.0f;
        int r = 0;
        for (; r + 1 < tv; r += 2) {
            float4 va = a4[(size_t)r * (L_ / 4) + tid];
            float4 vb = a4[(size_t)(r + 1) * (L_ / 4) + tid];
            attn_row(va, t0 + r,     ks, da, l0, m0, m1, m2, m3, s1, s2);
            attn_row(vb, t0 + r + 1, ks, da, l0, m0, m1, m2, m3, s1, s2);
        }
        if (r < tv) {
            float4 va = a4[(size_t)r * (L_ / 4) + tid];
            attn_row(va, t0 + r, ks, da, l0, m0, m1, m2, m3, s1, s2);
        }
        red2(s1, s2);
        if (tid == 0) { ws[WS_ATTN + a * 2] = s1; ws[WS_ATTN + a * 2 + 1] = s2; }

    } else if (blk < NB_MEL + NB_ATTN + NB_DUR) {
        // ---- duration MSE partials ----
        int d = blk - (NB_MEL + NB_ATTN);
        int base = d * (B_ * T_ / NB_DUR);         // 2048 elements per block
        float s = 0.0f;
        #pragma unroll
        for (int k = 0; k < (B_ * T_ / NB_DUR); k += 256) {
            int i = base + k + tid;
            int b = i >> 9, t = i & (T_ - 1);
            float diff = ldp[i] - logf((float)dur_t[i] + 1.0f);
            s += (t < xl_[b]) ? diff * diff : 0.0f;
        }
        float dummy = 0.0f;
        red2(s, dummy);
        if (tid == 0) ws[WS_DUR + d] = s;

    } else {
        // ---- speaker cosine partials: one block per b ----
        int b = blk - (NB_MEL + NB_ATTN + NB_DUR);
        float av = spk_p[b * DSPK_ + tid], cv = spk_e[b * DSPK_ + tid];
        float n = av * cv, x = av * av, y = cv * cv;
        red3(n, x, y);
        if (tid == 0) {
            ws[WS_SPK + 3 * b]     = n;
            ws[WS_SPK + 3 * b + 1] = x;
            ws[WS_SPK + 3 * b + 2] = y;
        }
    }
}

__global__ __launch_bounds__(256) void final_kernel(
    const int* __restrict__ mel_lens, const int* __restrict__ xl_,
    const float* __restrict__ ws, float* __restrict__ out) {
    int tid = threadIdx.x;
    __shared__ float sA[256], sB[256];
    __shared__ float perb[B_];
    __shared__ float res[4];   // [0]=mel_sum [1]=post_sum

    // mel partial reduction (512 pairs, 2 per thread)
    float s0 = 0.0f, s1 = 0.0f;
    for (int i = tid; i < NB_MEL; i += 256) { s0 += ws[2 * i]; s1 += ws[2 * i + 1]; }
    red2(s0, s1);
    if (tid == 0) { res[0] = s0; res[1] = s1; }
    __syncthreads();

    // attn per-b sums: thread = (b, quarter), each sums 8 chunks
    {
        int b = tid >> 3, c0 = (tid & 7) * 4;
        float t1 = 0.0f, t2 = 0.0f;
        #pragma unroll
        for (int c = c0; c < c0 + 4; ++c) {
            int a = b * 32 + c;
            t1 += ws[WS_ATTN + 2 * a];
            t2 += ws[WS_ATTN + 2 * a + 1];
        }
        sA[tid] = t1; sB[tid] = t2;
    }
    __syncthreads();
    if (tid < B_) {
        float t1 = 0.0f, t2 = 0.0f;
        #pragma unroll
        for (int k = 0; k < 8; ++k) { t1 += sA[tid * 8 + k]; t2 += sB[tid * 8 + k]; }
        perb[tid] = t2 / t1;                       // focus_b
    }
    __syncthreads();
    __shared__ float focus_mean, spk_mean, sm_s, cnt_s;
    if (tid == 0) {
        float f = 0.0f;
        for (int b = 0; b < B_; ++b) f += perb[b];
        focus_mean = f / (float)B_;
    }
    __syncthreads();

    // speaker cosine per b
    if (tid < B_) {
        float n = ws[WS_SPK + 3 * tid], x = ws[WS_SPK + 3 * tid + 1], y = ws[WS_SPK + 3 * tid + 2];
        const float eps = 1e-6f;
        float cosv = n / (fmaxf(sqrtf(x), eps) * fmaxf(sqrtf(y), eps));
        perb[tid] = 1.0f - cosv;
    }
    // lengths
    if (tid < B_) { sA[tid] = (float)min(xl_[tid], T_); sB[tid] = (float)min(mel_lens[tid], M_); }
    __syncthreads();
    if (tid == 0) {
        float spk = 0.0f, sm = 0.0f, cnt = 0.0f;
        for (int b = 0; b < B_; ++b) { spk += perb[b]; sm += sA[b]; cnt += sB[b]; }
        spk_mean = spk / (float)B_;
        sm_s = sm;
        cnt_s = cnt * (float)NMEL_;

        float sd = 0.0f;
        for (int d = 0; d < NB_DUR; ++d) sd += ws[WS_DUR + d];

        float mel  = res[0] / cnt_s;
        float post = res[1] / cnt_s;
        float dur  = sd / sm_s;
        float dia  = 0.1f * (-logf(focus_mean));
        out[0] = mel + post + dur + spk_mean + dia;
        out[1] = mel;
        out[2] = post;
        out[3] = spk_mean;
        out[4] = dur;
        out[5] = dia;
    }
}

extern "C" void kernel_launch(void* const* d_in, const int* in_sizes, int n_in,
                              void* d_out, int out_size, void* d_ws, size_t ws_size,
                              hipStream_t stream) {
    (void)in_sizes; (void)n_in; (void)out_size; (void)ws_size;
    const float* mel_t   = (const float*)d_in[2];
    const int*   mel_len = (const int*)  d_in[5];
    const int*   dur_t   = (const int*)  d_in[6];
    const float* mel_p   = (const float*)d_in[8];
    const float* post_p  = (const float*)d_in[9];
    const float* ldp     = (const float*)d_in[10];
    const float* spk_p   = (const float*)d_in[14];
    const float* spk_e   = (const float*)d_in[15];
    const float* attn    = (const float*)d_in[16];
    const int*   xl      = (const int*)  d_in[17];
    const int*   ll      = (const int*)  d_in[18];
    float* ws  = (float*)d_ws;
    float* out = (float*)d_out;

    hipLaunchKernelGGL(fused_kernel, dim3(NB_TOT), dim3(256), 0, stream,
                       mel_t, mel_p, post_p, mel_len, attn, xl, ll,
                       dur_t, ldp, spk_p, spk_e, ws);
    hipLaunchKernelGGL(final_kernel, dim3(1), dim3(256), 0, stream,
                       mel_len, xl, ws, out);
}